// Round 2
// baseline (803.097 us; speedup 1.0000x reference)
//
#include <hip/hip_runtime.h>
#include <math.h>

#define B_ 128
#define R_ 196
#define C_ 2048
#define A_ 1024
#define M_ (B_*R_)   // 25088

typedef short short8 __attribute__((ext_vector_type(8)));
typedef float f32x4  __attribute__((ext_vector_type(4)));

__device__ __forceinline__ short f2bf(float f) {
    unsigned u = __builtin_bit_cast(unsigned, f);
    u = (u + 0x7fffu + ((u >> 16) & 1u)) >> 16;   // round-to-nearest-even
    return (short)u;
}

__device__ __forceinline__ short8 pack8(const float4 a, const float4 b) {
    short8 r;
    r[0]=f2bf(a.x); r[1]=f2bf(a.y); r[2]=f2bf(a.z); r[3]=f2bf(a.w);
    r[4]=f2bf(b.x); r[5]=f2bf(b.y); r[6]=f2bf(b.z); r[7]=f2bf(b.w);
    return r;
}

__device__ __forceinline__ float gelu_exact(float x) {
    return 0.5f * x * (1.0f + erff(x * 0.70710678118654752f));
}

// scores[m] += sum_n gelu(image[m,:] . We[n,:] + be[n]) * Wf1[n]
// Tile: BM=128, BN=128, BK=64. 256 threads = 4 waves (2x2), each wave 64x64 (4x4 frags).
__global__ __launch_bounds__(256, 2) void score_gemm(
    const float* __restrict__ image, const float* __restrict__ We,
    const float* __restrict__ be,    const float* __restrict__ Wf,
    float* __restrict__ scores)
{
    __shared__ short8 ldsA[1024];   // 128 rows x 64 bf16 (8 slots of short8/row), XOR-swizzled
    __shared__ short8 ldsB[1024];

    const int t     = threadIdx.x;
    const int mtile = blockIdx.x >> 3;   // consecutive blocks share mtile -> A-rows L2/L3 reuse
    const int ntile = blockIdx.x & 7;
    const int m0 = mtile * 128;
    const int n0 = ntile * 128;

    // staging: each thread owns (row = t>>1, half-k = t&1) -> 32 f32 contiguous
    const int srow = t >> 1;
    const int skh  = t & 1;
    const float* pA = image + (size_t)(m0 + srow) * C_ + skh * 32;
    const float* pB = We    + (size_t)(n0 + srow) * C_ + skh * 32;
    const int wbase = srow * 8 + skh * 4;   // short8-slot base
    const int wswz  = srow & 7;

    const int lane = t & 63;
    const int wid  = t >> 6;
    const int wr = wid >> 1, wc = wid & 1;
    const int r16 = lane & 15, kg = lane >> 4;

    f32x4 acc[4][4];
    #pragma unroll
    for (int i = 0; i < 4; i++)
        #pragma unroll
        for (int j = 0; j < 4; j++) acc[i][j] = f32x4{0.f, 0.f, 0.f, 0.f};

    float4 ga[8], gb[8];
    #pragma unroll
    for (int j = 0; j < 8; j++) { ga[j] = ((const float4*)pA)[j]; gb[j] = ((const float4*)pB)[j]; }
    pA += 64; pB += 64;

    for (int kt = 0; kt < 32; ++kt) {
        // convert + write current tile to swizzled LDS
        #pragma unroll
        for (int s = 0; s < 4; s++) {
            ldsA[(wbase + s) ^ wswz] = pack8(ga[2*s], ga[2*s+1]);
            ldsB[(wbase + s) ^ wswz] = pack8(gb[2*s], gb[2*s+1]);
        }
        __syncthreads();

        // issue next-tile global loads; they complete under the MFMA section
        if (kt < 31) {
            #pragma unroll
            for (int j = 0; j < 8; j++) { ga[j] = ((const float4*)pA)[j]; gb[j] = ((const float4*)pB)[j]; }
            pA += 64; pB += 64;
        }

        short8 af[4][2], bfr[4][2];
        #pragma unroll
        for (int mi = 0; mi < 4; mi++) {
            const int row = wr*64 + mi*16 + r16;
            const int base = row*8 + kg;
            const int sw = row & 7;
            af[mi][0] = ldsA[ base      ^ sw];
            af[mi][1] = ldsA[(base + 4) ^ sw];
        }
        #pragma unroll
        for (int ni = 0; ni < 4; ni++) {
            const int row = wc*64 + ni*16 + r16;
            const int base = row*8 + kg;
            const int sw = row & 7;
            bfr[ni][0] = ldsB[ base      ^ sw];
            bfr[ni][1] = ldsB[(base + 4) ^ sw];
        }

        #pragma unroll
        for (int mi = 0; mi < 4; mi++)
            #pragma unroll
            for (int ni = 0; ni < 4; ni++) {
                acc[mi][ni] = __builtin_amdgcn_mfma_f32_16x16x32_bf16(af[mi][0], bfr[ni][0], acc[mi][ni], 0, 0, 0);
                acc[mi][ni] = __builtin_amdgcn_mfma_f32_16x16x32_bf16(af[mi][1], bfr[ni][1], acc[mi][ni], 0, 0, 0);
            }
        __syncthreads();
    }

    // epilogue: rowsum[m] = sum_n gelu(attn1 + be[n]) * Wf1[n]  (C/D: col=lane&15, row=(lane>>4)*4+i)
    float rowsum[4][4];
    #pragma unroll
    for (int mi = 0; mi < 4; mi++)
        #pragma unroll
        for (int i = 0; i < 4; i++) rowsum[mi][i] = 0.f;

    const int colbase = n0 + wc*64 + r16;
    #pragma unroll
    for (int ni = 0; ni < 4; ni++) {
        const int n_g = colbase + ni*16;
        const float ben = be[n_g];
        const float wfn = Wf[n_g];   // Wf1 = Wf[0:1024]
        #pragma unroll
        for (int mi = 0; mi < 4; mi++)
            #pragma unroll
            for (int i = 0; i < 4; i++)
                rowsum[mi][i] += gelu_exact(acc[mi][ni][i] + ben) * wfn;
    }

    #pragma unroll
    for (int mi = 0; mi < 4; mi++)
        #pragma unroll
        for (int i = 0; i < 4; i++) {
            float v = rowsum[mi][i];
            v += __shfl_xor(v, 1);
            v += __shfl_xor(v, 2);
            v += __shfl_xor(v, 4);
            v += __shfl_xor(v, 8);
            if (r16 == 0) {
                const int row_g = m0 + wr*64 + mi*16 + kg*4 + i;
                atomicAdd(&scores[row_g], v);
            }
        }
}

// in-place softmax over R=196 per batch row; scores buffer becomes alpha
__global__ void softmax_k(float* __restrict__ scores)
{
    const int b = blockIdx.x;
    const int t = threadIdx.x;   // 256
    float v = (t < R_) ? scores[b * R_ + t] : -3.4e38f;

    float m = v;
    #pragma unroll
    for (int off = 1; off < 64; off <<= 1) m = fmaxf(m, __shfl_xor(m, off));
    __shared__ float redm[4];
    if ((t & 63) == 0) redm[t >> 6] = m;
    __syncthreads();
    m = fmaxf(fmaxf(redm[0], redm[1]), fmaxf(redm[2], redm[3]));

    float e = (t < R_) ? expf(v - m) : 0.f;
    float s = e;
    #pragma unroll
    for (int off = 1; off < 64; off <<= 1) s += __shfl_xor(s, off);
    __shared__ float reds[4];
    if ((t & 63) == 0) reds[t >> 6] = s;
    __syncthreads();
    s = reds[0] + reds[1] + reds[2] + reds[3];

    if (t < R_) scores[b * R_ + t] = e / s;
}

// attended[b,c] = sum_r alpha[b,r] * image[b,r,c]
__global__ void attend_k(const float* __restrict__ image,
                         const float* __restrict__ alpha,
                         float* __restrict__ out)
{
    const int b     = blockIdx.y;
    const int chunk = blockIdx.x;       // 0..1, 1024 c each
    const int t     = threadIdx.x;      // 256

    __shared__ float sal[R_];
    if (t < R_) sal[t] = alpha[b * R_ + t];
    __syncthreads();

    const int c = chunk * 1024 + t * 4;
    const float* base = image + (size_t)b * R_ * C_ + c;
    float4 accv = {0.f, 0.f, 0.f, 0.f};
    #pragma unroll 4
    for (int r = 0; r < R_; ++r) {
        const float4 v = *(const float4*)(base + (size_t)r * C_);
        const float a = sal[r];
        accv.x += a * v.x;
        accv.y += a * v.y;
        accv.z += a * v.z;
        accv.w += a * v.w;
    }
    *(float4*)(out + b * C_ + c) = accv;
}

extern "C" void kernel_launch(void* const* d_in, const int* in_sizes, int n_in,
                              void* d_out, int out_size, void* d_ws, size_t ws_size,
                              hipStream_t stream) {
    const float* image = (const float*)d_in[0];
    const float* We    = (const float*)d_in[2];
    const float* be    = (const float*)d_in[3];
    const float* Wf    = (const float*)d_in[6];
    // decoder_hidden/Wd/bd/bf are per-row constants under softmax -> unused

    float* out   = (float*)d_out;
    float* alpha = out + (size_t)B_ * C_;   // scores accumulate here, softmaxed in place

    hipMemsetAsync(alpha, 0, (size_t)M_ * sizeof(float), stream);
    score_gemm<<<dim3(196 * 8), dim3(256), 0, stream>>>(image, We, be, Wf, alpha);
    softmax_k<<<dim3(B_), dim3(256), 0, stream>>>(alpha);
    attend_k<<<dim3(2, B_), dim3(256), 0, stream>>>(image, alpha, out);
}

// Round 5
// 512.414 us; speedup vs baseline: 1.5673x; 1.5673x over previous
//
#include <hip/hip_runtime.h>
#include <math.h>

#define B_ 128
#define R_ 196
#define C_ 2048
#define A_ 1024
#define M_ (B_*R_)                 // 25088
#define NIMG ((size_t)M_*C_)       // 51,380,224
#define NTOT (NIMG + (size_t)A_*C_)// 53,477,376

typedef short short8 __attribute__((ext_vector_type(8)));
typedef float f32x4  __attribute__((ext_vector_type(4)));

#define AS1 __attribute__((address_space(1)))
#define AS3 __attribute__((address_space(3)))

__device__ __forceinline__ short f2bf(float f) {
    unsigned u = __builtin_bit_cast(unsigned, f);
    u = (u + 0x7fffu + ((u >> 16) & 1u)) >> 16;   // round-to-nearest-even
    return (short)u;
}

__device__ __forceinline__ short8 pack8(const float4 a, const float4 b) {
    short8 r;
    r[0]=f2bf(a.x); r[1]=f2bf(a.y); r[2]=f2bf(a.z); r[3]=f2bf(a.w);
    r[4]=f2bf(b.x); r[5]=f2bf(b.y); r[6]=f2bf(b.z); r[7]=f2bf(b.w);
    return r;
}

__device__ __forceinline__ float gelu_exact(float x) {
    return 0.5f * x * (1.0f + erff(x * 0.70710678118654752f));
}

// ---------- prepass: f32 -> bf16 (image then We, contiguous in ws) ----------
__global__ __launch_bounds__(256) void tobf16_k(const float* __restrict__ img,
                                                const float* __restrict__ We,
                                                ushort* __restrict__ dst)
{
    size_t i = ((size_t)blockIdx.x * blockDim.x + threadIdx.x) * 8;
    const size_t stride = (size_t)gridDim.x * blockDim.x * 8;
    for (; i < NTOT; i += stride) {
        const float* s = (i < NIMG) ? (img + i) : (We + (i - NIMG));
        const float4 a = ((const float4*)s)[0];
        const float4 b = ((const float4*)s)[1];
        *(short8*)(dst + i) = pack8(a, b);
    }
}

// ---------- bf16 GEMM: scores[m] += sum_n gelu(A[m,:].B[n,:] + be[n]) * Wf1[n] ----------
// 128x128 tile, BK=64, 4 waves (2x2) x 4x4 frags of 16x16x32.
// global_load_lds width=16, linear LDS dest; XOR swizzle applied on the global
// SOURCE address and on the ds_read address (same involution, rule #21).
__global__ __launch_bounds__(256, 3) void score_gemm_bf16(
    const ushort* __restrict__ Abf, const ushort* __restrict__ Bbf,
    const float* __restrict__ be,   const float* __restrict__ Wf,
    float* __restrict__ scores)
{
    __shared__ ushort ldsA[128*64];   // 16 KB
    __shared__ ushort ldsB[128*64];   // 16 KB

    const int t    = threadIdx.x;
    const int lane = t & 63;
    const int wid  = t >> 6;

    // T1 chunked XCD swizzle: 1568 blocks = 8 * 196
    const int L     = ((blockIdx.x & 7) * 196) + (blockIdx.x >> 3);
    const int mtile = L >> 3;
    const int ntile = L & 7;
    const int m0 = mtile * 128;
    const int n0 = ntile * 128;

    // staging source offsets: slot sidx=(wid*4+i)*64+lane; row=sidx>>3, sl=sidx&7,
    // logical k-chunk kk = sl ^ (row&7); src byte = row*4096 + kt*128 + kk*16
    int soff[4];
    #pragma unroll
    for (int i = 0; i < 4; i++) {
        const int sidx = (wid*4 + i)*64 + lane;
        const int row  = sidx >> 3;
        const int kk   = (sidx & 7) ^ (row & 7);
        soff[i] = row*4096 + kk*16;
    }
    const char* Ap = (const char*)Abf + (size_t)m0 * 4096;
    const char* Bp = (const char*)Bbf + (size_t)n0 * 4096;
    char* lA = (char*)ldsA;
    char* lB = (char*)ldsB;
    const int lbase = wid * 4096;

    const int wr = wid >> 1, wc = wid & 1;
    const int r16 = lane & 15, kg = lane >> 4;

    int arow[4], brow[4];
    #pragma unroll
    for (int mi = 0; mi < 4; mi++) arow[mi] = wr*64 + mi*16 + r16;
    #pragma unroll
    for (int ni = 0; ni < 4; ni++) brow[ni] = wc*64 + ni*16 + r16;

    f32x4 acc[4][4];
    #pragma unroll
    for (int i = 0; i < 4; i++)
        #pragma unroll
        for (int j = 0; j < 4; j++) acc[i][j] = f32x4{0.f,0.f,0.f,0.f};

    const short8* sA = (const short8*)ldsA;
    const short8* sB = (const short8*)ldsB;

    for (int kt = 0; kt < 32; ++kt) {
        __syncthreads();   // prev tile's ds_reads complete before overwrite
        const int kb = kt * 128;
        #pragma unroll
        for (int i = 0; i < 4; i++)
            __builtin_amdgcn_global_load_lds((AS1 void*)(Ap + soff[i] + kb),
                                             (AS3 void*)(lA + lbase + i*1024), 16, 0, 0);
        #pragma unroll
        for (int i = 0; i < 4; i++)
            __builtin_amdgcn_global_load_lds((AS1 void*)(Bp + soff[i] + kb),
                                             (AS3 void*)(lB + lbase + i*1024), 16, 0, 0);
        __syncthreads();   // vmcnt(0) drained before barrier -> tile resident

        #pragma unroll
        for (int s = 0; s < 2; s++) {
            short8 af[4], bfr[4];
            const int kk = s*4 + kg;
            #pragma unroll
            for (int mi = 0; mi < 4; mi++)
                af[mi] = sA[arow[mi]*8 + (kk ^ (arow[mi] & 7))];
            #pragma unroll
            for (int ni = 0; ni < 4; ni++)
                bfr[ni] = sB[brow[ni]*8 + (kk ^ (brow[ni] & 7))];
            #pragma unroll
            for (int mi = 0; mi < 4; mi++)
                #pragma unroll
                for (int ni = 0; ni < 4; ni++)
                    acc[mi][ni] = __builtin_amdgcn_mfma_f32_16x16x32_bf16(af[mi], bfr[ni], acc[mi][ni], 0, 0, 0);
        }
    }

    // epilogue: rowsum over n of gelu(acc + be[n]) * Wf1[n]; C/D: col=lane&15, row=(lane>>4)*4+i
    float rowsum[4][4];
    #pragma unroll
    for (int mi = 0; mi < 4; mi++)
        #pragma unroll
        for (int i = 0; i < 4; i++) rowsum[mi][i] = 0.f;

    const int colbase = n0 + wc*64 + r16;
    #pragma unroll
    for (int ni = 0; ni < 4; ni++) {
        const int n_g = colbase + ni*16;
        const float ben = be[n_g];
        const float wfn = Wf[n_g];
        #pragma unroll
        for (int mi = 0; mi < 4; mi++)
            #pragma unroll
            for (int i = 0; i < 4; i++)
                rowsum[mi][i] += gelu_exact(acc[mi][ni][i] + ben) * wfn;
    }

    #pragma unroll
    for (int mi = 0; mi < 4; mi++)
        #pragma unroll
        for (int i = 0; i < 4; i++) {
            float v = rowsum[mi][i];
            v += __shfl_xor(v, 1);
            v += __shfl_xor(v, 2);
            v += __shfl_xor(v, 4);
            v += __shfl_xor(v, 8);
            if (r16 == 0) {
                const int row_g = m0 + wr*64 + mi*16 + kg*4 + i;
                atomicAdd(&scores[row_g], v);
            }
        }
}

// ---------- fallback f32 GEMM (round-2 passing version) ----------
__global__ __launch_bounds__(256, 2) void score_gemm(
    const float* __restrict__ image, const float* __restrict__ We,
    const float* __restrict__ be,    const float* __restrict__ Wf,
    float* __restrict__ scores)
{
    __shared__ short8 ldsA[1024];
    __shared__ short8 ldsB[1024];

    const int t     = threadIdx.x;
    const int mtile = blockIdx.x >> 3;
    const int ntile = blockIdx.x & 7;
    const int m0 = mtile * 128;
    const int n0 = ntile * 128;

    const int srow = t >> 1;
    const int skh  = t & 1;
    const float* pA = image + (size_t)(m0 + srow) * C_ + skh * 32;
    const float* pB = We    + (size_t)(n0 + srow) * C_ + skh * 32;
    const int wbase = srow * 8 + skh * 4;
    const int wswz  = srow & 7;

    const int lane = t & 63;
    const int wid  = t >> 6;
    const int wr = wid >> 1, wc = wid & 1;
    const int r16 = lane & 15, kg = lane >> 4;

    f32x4 acc[4][4];
    #pragma unroll
    for (int i = 0; i < 4; i++)
        #pragma unroll
        for (int j = 0; j < 4; j++) acc[i][j] = f32x4{0.f,0.f,0.f,0.f};

    float4 ga[8], gb[8];
    #pragma unroll
    for (int j = 0; j < 8; j++) { ga[j] = ((const float4*)pA)[j]; gb[j] = ((const float4*)pB)[j]; }
    pA += 64; pB += 64;

    for (int kt = 0; kt < 32; ++kt) {
        #pragma unroll
        for (int s = 0; s < 4; s++) {
            ldsA[(wbase + s) ^ wswz] = pack8(ga[2*s], ga[2*s+1]);
            ldsB[(wbase + s) ^ wswz] = pack8(gb[2*s], gb[2*s+1]);
        }
        __syncthreads();
        if (kt < 31) {
            #pragma unroll
            for (int j = 0; j < 8; j++) { ga[j] = ((const float4*)pA)[j]; gb[j] = ((const float4*)pB)[j]; }
            pA += 64; pB += 64;
        }
        short8 af[4][2], bfr[4][2];
        #pragma unroll
        for (int mi = 0; mi < 4; mi++) {
            const int row = wr*64 + mi*16 + r16;
            const int base = row*8 + kg;
            const int sw = row & 7;
            af[mi][0] = ldsA[ base      ^ sw];
            af[mi][1] = ldsA[(base + 4) ^ sw];
        }
        #pragma unroll
        for (int ni = 0; ni < 4; ni++) {
            const int row = wc*64 + ni*16 + r16;
            const int base = row*8 + kg;
            const int sw = row & 7;
            bfr[ni][0] = ldsB[ base      ^ sw];
            bfr[ni][1] = ldsB[(base + 4) ^ sw];
        }
        #pragma unroll
        for (int mi = 0; mi < 4; mi++)
            #pragma unroll
            for (int ni = 0; ni < 4; ni++) {
                acc[mi][ni] = __builtin_amdgcn_mfma_f32_16x16x32_bf16(af[mi][0], bfr[ni][0], acc[mi][ni], 0, 0, 0);
                acc[mi][ni] = __builtin_amdgcn_mfma_f32_16x16x32_bf16(af[mi][1], bfr[ni][1], acc[mi][ni], 0, 0, 0);
            }
        __syncthreads();
    }

    float rowsum[4][4];
    #pragma unroll
    for (int mi = 0; mi < 4; mi++)
        #pragma unroll
        for (int i = 0; i < 4; i++) rowsum[mi][i] = 0.f;

    const int colbase = n0 + wc*64 + r16;
    #pragma unroll
    for (int ni = 0; ni < 4; ni++) {
        const int n_g = colbase + ni*16;
        const float ben = be[n_g];
        const float wfn = Wf[n_g];
        #pragma unroll
        for (int mi = 0; mi < 4; mi++)
            #pragma unroll
            for (int i = 0; i < 4; i++)
                rowsum[mi][i] += gelu_exact(acc[mi][ni][i] + ben) * wfn;
    }

    #pragma unroll
    for (int mi = 0; mi < 4; mi++)
        #pragma unroll
        for (int i = 0; i < 4; i++) {
            float v = rowsum[mi][i];
            v += __shfl_xor(v, 1);
            v += __shfl_xor(v, 2);
            v += __shfl_xor(v, 4);
            v += __shfl_xor(v, 8);
            if (r16 == 0) {
                const int row_g = m0 + wr*64 + mi*16 + kg*4 + i;
                atomicAdd(&scores[row_g], v);
            }
        }
}

// ---------- softmax over R=196, in place ----------
__global__ void softmax_k(float* __restrict__ scores)
{
    const int b = blockIdx.x;
    const int t = threadIdx.x;
    float v = (t < R_) ? scores[b * R_ + t] : -3.4e38f;

    float m = v;
    #pragma unroll
    for (int off = 1; off < 64; off <<= 1) m = fmaxf(m, __shfl_xor(m, off));
    __shared__ float redm[4];
    if ((t & 63) == 0) redm[t >> 6] = m;
    __syncthreads();
    m = fmaxf(fmaxf(redm[0], redm[1]), fmaxf(redm[2], redm[3]));

    float e = (t < R_) ? expf(v - m) : 0.f;
    float s = e;
    #pragma unroll
    for (int off = 1; off < 64; off <<= 1) s += __shfl_xor(s, off);
    __shared__ float reds[4];
    if ((t & 63) == 0) reds[t >> 6] = s;
    __syncthreads();
    s = reds[0] + reds[1] + reds[2] + reds[3];

    if (t < R_) scores[b * R_ + t] = e / s;
}

// ---------- attended[b,c] = sum_r alpha[b,r] * image[b,r,c] ----------
__global__ void attend_k(const float* __restrict__ image,
                         const float* __restrict__ alpha,
                         float* __restrict__ out)
{
    const int b     = blockIdx.y;
    const int chunk = blockIdx.x;
    const int t     = threadIdx.x;

    __shared__ float sal[R_];
    if (t < R_) sal[t] = alpha[b * R_ + t];
    __syncthreads();

    const int c = chunk * 1024 + t * 4;
    const float* base = image + (size_t)b * R_ * C_ + c;
    float4 accv = {0.f, 0.f, 0.f, 0.f};
    #pragma unroll 4
    for (int r = 0; r < R_; ++r) {
        const float4 v = *(const float4*)(base + (size_t)r * C_);
        const float a = sal[r];
        accv.x += a * v.x;
        accv.y += a * v.y;
        accv.z += a * v.z;
        accv.w += a * v.w;
    }
    *(float4*)(out + b * C_ + c) = accv;
}

extern "C" void kernel_launch(void* const* d_in, const int* in_sizes, int n_in,
                              void* d_out, int out_size, void* d_ws, size_t ws_size,
                              hipStream_t stream) {
    const float* image = (const float*)d_in[0];
    const float* We    = (const float*)d_in[2];
    const float* be    = (const float*)d_in[3];
    const float* Wf    = (const float*)d_in[6];
    // decoder path (decoder_hidden/Wd/bd/bf) is constant per batch row under softmax -> unused

    float* out   = (float*)d_out;
    float* alpha = out + (size_t)B_ * C_;   // scores accumulate here, softmaxed in place

    hipMemsetAsync(alpha, 0, (size_t)M_ * sizeof(float), stream);

    if (ws_size >= NTOT * 2) {
        ushort* Abf = (ushort*)d_ws;            // [25088][2048] bf16
        ushort* Bbf = Abf + NIMG;               // [1024][2048] bf16
        tobf16_k<<<dim3(2048), dim3(256), 0, stream>>>(image, We, Abf);
        score_gemm_bf16<<<dim3(196*8), dim3(256), 0, stream>>>(Abf, Bbf, be, Wf, alpha);
    } else {
        score_gemm<<<dim3(196*8), dim3(256), 0, stream>>>(image, We, be, Wf, alpha);
    }
    softmax_k<<<dim3(B_), dim3(256), 0, stream>>>(alpha);
    attend_k<<<dim3(2, B_), dim3(256), 0, stream>>>(image, alpha, out);
}

// Round 6
// 507.374 us; speedup vs baseline: 1.5828x; 1.0099x over previous
//
#include <hip/hip_runtime.h>
#include <math.h>

#define B_ 128
#define R_ 196
#define C_ 2048
#define A_ 1024
#define M_ (B_*R_)                 // 25088
#define NIMG ((size_t)M_*C_)       // 51,380,224
#define NTOT (NIMG + (size_t)A_*C_)// 53,477,376

typedef short short8 __attribute__((ext_vector_type(8)));
typedef float f32x4  __attribute__((ext_vector_type(4)));

#define AS1 __attribute__((address_space(1)))
#define AS3 __attribute__((address_space(3)))

__device__ __forceinline__ short f2bf(float f) {
    unsigned u = __builtin_bit_cast(unsigned, f);
    u = (u + 0x7fffu + ((u >> 16) & 1u)) >> 16;   // round-to-nearest-even
    return (short)u;
}

__device__ __forceinline__ short8 pack8(const float4 a, const float4 b) {
    short8 r;
    r[0]=f2bf(a.x); r[1]=f2bf(a.y); r[2]=f2bf(a.z); r[3]=f2bf(a.w);
    r[4]=f2bf(b.x); r[5]=f2bf(b.y); r[6]=f2bf(b.z); r[7]=f2bf(b.w);
    return r;
}

__device__ __forceinline__ float gelu_exact(float x) {
    return 0.5f * x * (1.0f + erff(x * 0.70710678118654752f));
}

// ---------- prepass: f32 -> bf16 (image then We, contiguous in ws) ----------
// exact grid: 26112 blocks x 256 thr x 8 elem = NTOT
__global__ __launch_bounds__(256) void tobf16_k(const float* __restrict__ img,
                                                const float* __restrict__ We,
                                                ushort* __restrict__ dst)
{
    const size_t i = ((size_t)blockIdx.x * 256 + threadIdx.x) * 8;
    const float* s = (i < NIMG) ? (img + i) : (We + (i - NIMG));
    const float4 a = ((const float4*)s)[0];
    const float4 b = ((const float4*)s)[1];
    *(short8*)(dst + i) = pack8(a, b);
}

// ---------- bf16 GEMM: scores[m] += sum_n gelu(A[m,:].B[n,:] + be[n]) * Wf1[n] ----------
// 128x128 tile, BK=64, 4 waves (2x2) x 4x4 frags of 16x16x32.
// T3 minimum 2-phase: double-buffered LDS; stage tile k+1 BEFORE computing tile k;
// one counted vmcnt(0) + raw s_barrier per iter (not __syncthreads, which would
// drain the just-issued prefetch). sched_barrier(0) fences per rule #18.
__global__ __launch_bounds__(256, 2) void score_gemm_bf16(
    const ushort* __restrict__ Abf, const ushort* __restrict__ Bbf,
    const float* __restrict__ be,   const float* __restrict__ Wf,
    float* __restrict__ scores)
{
    __shared__ char lds[2][32768];   // [buf][ A:16KB | B:16KB ]  = 64 KB total

    const int t    = threadIdx.x;
    const int lane = t & 63;
    const int wid  = t >> 6;

    // T1 chunked XCD swizzle: 1568 blocks = 8 * 196
    const int L     = ((blockIdx.x & 7) * 196) + (blockIdx.x >> 3);
    const int mtile = L >> 3;
    const int ntile = L & 7;
    const int m0 = mtile * 128;
    const int n0 = ntile * 128;

    // staging source offsets: LDS slot sidx=(wid*4+i)*64+lane (linear dest);
    // row=sidx>>3, logical k-chunk kk=(sidx&7)^(row&7) -> pre-swizzled SOURCE (rule #21)
    int soff[4];
    #pragma unroll
    for (int i = 0; i < 4; i++) {
        const int sidx = (wid*4 + i)*64 + lane;
        const int row  = sidx >> 3;
        const int kk   = (sidx & 7) ^ (row & 7);
        soff[i] = row*4096 + kk*16;
    }
    const char* Ap = (const char*)Abf + (size_t)m0 * 4096;
    const char* Bp = (const char*)Bbf + (size_t)n0 * 4096;
    const int lbase = wid * 4096;

    const int wr = wid >> 1, wc = wid & 1;
    const int r16 = lane & 15, kg = lane >> 4;

    int arow[4], brow[4];
    #pragma unroll
    for (int mi = 0; mi < 4; mi++) arow[mi] = wr*64 + mi*16 + r16;
    #pragma unroll
    for (int ni = 0; ni < 4; ni++) brow[ni] = wc*64 + ni*16 + r16;

    f32x4 acc[4][4];
    #pragma unroll
    for (int i = 0; i < 4; i++)
        #pragma unroll
        for (int j = 0; j < 4; j++) acc[i][j] = f32x4{0.f,0.f,0.f,0.f};

    #define STAGE(BUF, KT) do {                                                  \
        const int kb_ = (KT) * 128;                                              \
        char* dA_ = &lds[BUF][0]     + lbase;                                    \
        char* dB_ = &lds[BUF][16384] + lbase;                                    \
        _Pragma("unroll")                                                        \
        for (int i_ = 0; i_ < 4; i_++)                                           \
            __builtin_amdgcn_global_load_lds((AS1 void*)(Ap + soff[i_] + kb_),   \
                                             (AS3 void*)(dA_ + i_*1024), 16, 0, 0); \
        _Pragma("unroll")                                                        \
        for (int i_ = 0; i_ < 4; i_++)                                           \
            __builtin_amdgcn_global_load_lds((AS1 void*)(Bp + soff[i_] + kb_),   \
                                             (AS3 void*)(dB_ + i_*1024), 16, 0, 0); \
    } while (0)

    // prologue: tile 0 into buf 0
    STAGE(0, 0);
    asm volatile("s_waitcnt vmcnt(0)" ::: "memory");
    __builtin_amdgcn_s_barrier();
    __builtin_amdgcn_sched_barrier(0);

    for (int kt = 0; kt < 32; ++kt) {
        const int cur = kt & 1;
        if (kt < 31) STAGE(cur ^ 1, kt + 1);   // prefetch next tile (other buffer)

        const short8* sA = (const short8*)&lds[cur][0];
        const short8* sB = (const short8*)&lds[cur][16384];
        #pragma unroll
        for (int s = 0; s < 2; s++) {
            short8 af[4], bfr[4];
            const int kk = s*4 + kg;
            #pragma unroll
            for (int mi = 0; mi < 4; mi++)
                af[mi] = sA[arow[mi]*8 + (kk ^ (arow[mi] & 7))];
            #pragma unroll
            for (int ni = 0; ni < 4; ni++)
                bfr[ni] = sB[brow[ni]*8 + (kk ^ (brow[ni] & 7))];
            #pragma unroll
            for (int mi = 0; mi < 4; mi++)
                #pragma unroll
                for (int ni = 0; ni < 4; ni++)
                    acc[mi][ni] = __builtin_amdgcn_mfma_f32_16x16x32_bf16(af[mi], bfr[ni], acc[mi][ni], 0, 0, 0);
        }

        if (kt < 31) {
            // drain this iter's prefetch (issued ~32 MFMAs ago), sync, fence
            asm volatile("s_waitcnt vmcnt(0)" ::: "memory");
            __builtin_amdgcn_s_barrier();
            __builtin_amdgcn_sched_barrier(0);
        }
    }
    #undef STAGE

    // epilogue: rowsum over n of gelu(acc + be[n]) * Wf1[n]; C/D: col=lane&15, row=(lane>>4)*4+i
    float rowsum[4][4];
    #pragma unroll
    for (int mi = 0; mi < 4; mi++)
        #pragma unroll
        for (int i = 0; i < 4; i++) rowsum[mi][i] = 0.f;

    const int colbase = n0 + wc*64 + r16;
    #pragma unroll
    for (int ni = 0; ni < 4; ni++) {
        const int n_g = colbase + ni*16;
        const float ben = be[n_g];
        const float wfn = Wf[n_g];
        #pragma unroll
        for (int mi = 0; mi < 4; mi++)
            #pragma unroll
            for (int i = 0; i < 4; i++)
                rowsum[mi][i] += gelu_exact(acc[mi][ni][i] + ben) * wfn;
    }

    #pragma unroll
    for (int mi = 0; mi < 4; mi++)
        #pragma unroll
        for (int i = 0; i < 4; i++) {
            float v = rowsum[mi][i];
            v += __shfl_xor(v, 1);
            v += __shfl_xor(v, 2);
            v += __shfl_xor(v, 4);
            v += __shfl_xor(v, 8);
            if (r16 == 0) {
                const int row_g = m0 + wr*64 + mi*16 + kg*4 + i;
                atomicAdd(&scores[row_g], v);
            }
        }
}

// ---------- fallback f32 GEMM (round-2 passing version) ----------
__global__ __launch_bounds__(256, 2) void score_gemm(
    const float* __restrict__ image, const float* __restrict__ We,
    const float* __restrict__ be,    const float* __restrict__ Wf,
    float* __restrict__ scores)
{
    __shared__ short8 ldsA[1024];
    __shared__ short8 ldsB[1024];

    const int t     = threadIdx.x;
    const int mtile = blockIdx.x >> 3;
    const int ntile = blockIdx.x & 7;
    const int m0 = mtile * 128;
    const int n0 = ntile * 128;

    const int srow = t >> 1;
    const int skh  = t & 1;
    const float* pA = image + (size_t)(m0 + srow) * C_ + skh * 32;
    const float* pB = We    + (size_t)(n0 + srow) * C_ + skh * 32;
    const int wbase = srow * 8 + skh * 4;
    const int wswz  = srow & 7;

    const int lane = t & 63;
    const int wid  = t >> 6;
    const int wr = wid >> 1, wc = wid & 1;
    const int r16 = lane & 15, kg = lane >> 4;

    f32x4 acc[4][4];
    #pragma unroll
    for (int i = 0; i < 4; i++)
        #pragma unroll
        for (int j = 0; j < 4; j++) acc[i][j] = f32x4{0.f,0.f,0.f,0.f};

    float4 ga[8], gb[8];
    #pragma unroll
    for (int j = 0; j < 8; j++) { ga[j] = ((const float4*)pA)[j]; gb[j] = ((const float4*)pB)[j]; }
    pA += 64; pB += 64;

    for (int kt = 0; kt < 32; ++kt) {
        #pragma unroll
        for (int s = 0; s < 4; s++) {
            ldsA[(wbase + s) ^ wswz] = pack8(ga[2*s], ga[2*s+1]);
            ldsB[(wbase + s) ^ wswz] = pack8(gb[2*s], gb[2*s+1]);
        }
        __syncthreads();
        if (kt < 31) {
            #pragma unroll
            for (int j = 0; j < 8; j++) { ga[j] = ((const float4*)pA)[j]; gb[j] = ((const float4*)pB)[j]; }
            pA += 64; pB += 64;
        }
        short8 af[4][2], bfr[4][2];
        #pragma unroll
        for (int mi = 0; mi < 4; mi++) {
            const int row = wr*64 + mi*16 + r16;
            const int base = row*8 + kg;
            const int sw = row & 7;
            af[mi][0] = ldsA[ base      ^ sw];
            af[mi][1] = ldsA[(base + 4) ^ sw];
        }
        #pragma unroll
        for (int ni = 0; ni < 4; ni++) {
            const int row = wc*64 + ni*16 + r16;
            const int base = row*8 + kg;
            const int sw = row & 7;
            bfr[ni][0] = ldsB[ base      ^ sw];
            bfr[ni][1] = ldsB[(base + 4) ^ sw];
        }
        #pragma unroll
        for (int mi = 0; mi < 4; mi++)
            #pragma unroll
            for (int ni = 0; ni < 4; ni++) {
                acc[mi][ni] = __builtin_amdgcn_mfma_f32_16x16x32_bf16(af[mi][0], bfr[ni][0], acc[mi][ni], 0, 0, 0);
                acc[mi][ni] = __builtin_amdgcn_mfma_f32_16x16x32_bf16(af[mi][1], bfr[ni][1], acc[mi][ni], 0, 0, 0);
            }
        __syncthreads();
    }

    float rowsum[4][4];
    #pragma unroll
    for (int mi = 0; mi < 4; mi++)
        #pragma unroll
        for (int i = 0; i < 4; i++) rowsum[mi][i] = 0.f;

    const int colbase = n0 + wc*64 + r16;
    #pragma unroll
    for (int ni = 0; ni < 4; ni++) {
        const int n_g = colbase + ni*16;
        const float ben = be[n_g];
        const float wfn = Wf[n_g];
        #pragma unroll
        for (int mi = 0; mi < 4; mi++)
            #pragma unroll
            for (int i = 0; i < 4; i++)
                rowsum[mi][i] += gelu_exact(acc[mi][ni][i] + ben) * wfn;
    }

    #pragma unroll
    for (int mi = 0; mi < 4; mi++)
        #pragma unroll
        for (int i = 0; i < 4; i++) {
            float v = rowsum[mi][i];
            v += __shfl_xor(v, 1);
            v += __shfl_xor(v, 2);
            v += __shfl_xor(v, 4);
            v += __shfl_xor(v, 8);
            if (r16 == 0) {
                const int row_g = m0 + wr*64 + mi*16 + kg*4 + i;
                atomicAdd(&scores[row_g], v);
            }
        }
}

// ---------- softmax over R=196, in place ----------
__global__ void softmax_k(float* __restrict__ scores)
{
    const int b = blockIdx.x;
    const int t = threadIdx.x;
    float v = (t < R_) ? scores[b * R_ + t] : -3.4e38f;

    float m = v;
    #pragma unroll
    for (int off = 1; off < 64; off <<= 1) m = fmaxf(m, __shfl_xor(m, off));
    __shared__ float redm[4];
    if ((t & 63) == 0) redm[t >> 6] = m;
    __syncthreads();
    m = fmaxf(fmaxf(redm[0], redm[1]), fmaxf(redm[2], redm[3]));

    float e = (t < R_) ? expf(v - m) : 0.f;
    float s = e;
    #pragma unroll
    for (int off = 1; off < 64; off <<= 1) s += __shfl_xor(s, off);
    __shared__ float reds[4];
    if ((t & 63) == 0) reds[t >> 6] = s;
    __syncthreads();
    s = reds[0] + reds[1] + reds[2] + reds[3];

    if (t < R_) scores[b * R_ + t] = e / s;
}

// ---------- attended[b,c] = sum_r alpha[b,r] * image[b,r,c] ----------
__global__ __launch_bounds__(128) void attend_k(const float* __restrict__ image,
                                                const float* __restrict__ alpha,
                                                float* __restrict__ out)
{
    const int b     = blockIdx.y;
    const int chunk = blockIdx.x;       // 0..3, 512 c each
    const int t     = threadIdx.x;      // 128

    __shared__ float sal[R_];
    if (t < R_) {
        sal[t] = alpha[b * R_ + t];
        if (t + 128 < R_) sal[t + 128] = alpha[b * R_ + t + 128];
    }
    __syncthreads();

    const int c = chunk * 512 + t * 4;
    const float* base = image + (size_t)b * R_ * C_ + c;
    float4 accv = {0.f, 0.f, 0.f, 0.f};
    #pragma unroll 4
    for (int r = 0; r < R_; ++r) {
        const float4 v = *(const float4*)(base + (size_t)r * C_);
        const float a = sal[r];
        accv.x += a * v.x;
        accv.y += a * v.y;
        accv.z += a * v.z;
        accv.w += a * v.w;
    }
    *(float4*)(out + b * C_ + c) = accv;
}

extern "C" void kernel_launch(void* const* d_in, const int* in_sizes, int n_in,
                              void* d_out, int out_size, void* d_ws, size_t ws_size,
                              hipStream_t stream) {
    const float* image = (const float*)d_in[0];
    const float* We    = (const float*)d_in[2];
    const float* be    = (const float*)d_in[3];
    const float* Wf    = (const float*)d_in[6];
    // decoder path (decoder_hidden/Wd/bd/bf) is constant per batch row under softmax -> unused

    float* out   = (float*)d_out;
    float* alpha = out + (size_t)B_ * C_;   // scores accumulate here, softmaxed in place

    hipMemsetAsync(alpha, 0, (size_t)M_ * sizeof(float), stream);

    if (ws_size >= NTOT * 2) {
        ushort* Abf = (ushort*)d_ws;            // [25088][2048] bf16
        ushort* Bbf = Abf + NIMG;               // [1024][2048] bf16
        tobf16_k<<<dim3(26112), dim3(256), 0, stream>>>(image, We, Abf);
        score_gemm_bf16<<<dim3(196*8), dim3(256), 0, stream>>>(Abf, Bbf, be, Wf, alpha);
    } else {
        score_gemm<<<dim3(196*8), dim3(256), 0, stream>>>(image, We, be, Wf, alpha);
    }
    softmax_k<<<dim3(B_), dim3(256), 0, stream>>>(alpha);
    attend_k<<<dim3(4, B_), dim3(128), 0, stream>>>(image, alpha, out);
}